// Round 1
// baseline (1030.283 us; speedup 1.0000x reference)
//
#include <hip/hip_runtime.h>

#define H_    112
#define W_    112
#define CIN   64
#define COUT  64
#define B_    32
#define TILE  16
#define NTILE (W_ / TILE)          // 7
#define TPB   (NTILE * NTILE)      // 49 tiles per image

// ---------------------------------------------------------------------------
// Pre-kernel: quantize w -> sign(w) and transpose [cout][cin][9] -> [cin][cout][9]
// so the main kernel's per-cin weight slice is 2304 contiguous bytes
// (scalar-load friendly, wave-uniform access).
// ---------------------------------------------------------------------------
__global__ void quantize_transpose_w(const float* __restrict__ w,
                                     float* __restrict__ wq) {
    int i = blockIdx.x * blockDim.x + threadIdx.x;   // over COUT*CIN*9
    if (i >= COUT * CIN * 9) return;
    int k   = i % 9;
    int cin = (i / 9) % CIN;
    int co  = i / (9 * CIN);
    float v = w[i];
    float q = (v > 0.f) ? 1.f : ((v < 0.f) ? -1.f : 0.f);
    wq[(cin * COUT + co) * 9 + k] = q;
}

// ---------------------------------------------------------------------------
// Direct 3x3 conv, stride 1, pad 1.
// Block = 256 threads = one 16x16 spatial tile of one batch image.
// Each thread: 1 spatial position, all 64 cout accumulators in VGPRs.
// Per cin: stage 18x18 halo tile in LDS, 9 LDS reads, 576 FMAs with
// wave-uniform (scalar) weights.
// ---------------------------------------------------------------------------
template <bool TRANSPOSED>
__global__ __launch_bounds__(256) void conv3x3_direct(
    const float* __restrict__ x, const float* __restrict__ wq,
    const float* __restrict__ bias, const float* __restrict__ scale,
    float* __restrict__ out) {
    __shared__ float xt[18 * 18];

    const int tid = threadIdx.x;
    const int b   = blockIdx.x / TPB;
    const int t   = blockIdx.x % TPB;
    const int th  = (t / NTILE) * TILE;
    const int tw  = (t % NTILE) * TILE;
    const int ty  = tid >> 4;
    const int tx  = tid & 15;
    const int oh  = th + ty;
    const int ow  = tw + tx;

    float acc[COUT];
#pragma unroll
    for (int i = 0; i < COUT; ++i) acc[i] = 0.f;

    const float* xb = x + (size_t)b * (CIN * H_ * W_);

    for (int cin = 0; cin < CIN; ++cin) {
        __syncthreads();  // previous iteration's LDS reads done before overwrite
        for (int i = tid; i < 18 * 18; i += 256) {
            int r = i / 18, c = i % 18;
            int gh = th + r - 1, gw = tw + c - 1;
            float v = 0.f;
            if ((unsigned)gh < (unsigned)H_ && (unsigned)gw < (unsigned)W_)
                v = xb[cin * (H_ * W_) + gh * W_ + gw];
            xt[i] = v;
        }
        __syncthreads();

        float xv[9];
#pragma unroll
        for (int kh = 0; kh < 3; ++kh)
#pragma unroll
            for (int kw = 0; kw < 3; ++kw)
                xv[kh * 3 + kw] = xt[(ty + kh) * 18 + (tx + kw)];

#pragma unroll
        for (int co = 0; co < COUT; ++co) {
            const float* wc = TRANSPOSED ? (wq + (cin * COUT + co) * 9)
                                         : (wq + (co * CIN + cin) * 9);
#pragma unroll
            for (int k = 0; k < 9; ++k) {
                float wv = wc[k];
                float q;
                if (TRANSPOSED) {
                    q = wv;  // already sign-quantized by pre-kernel
                } else {
                    q = (wv > 0.f) ? 1.f : ((wv < 0.f) ? -1.f : 0.f);
                }
                acc[co] = fmaf(q, xv[k], acc[co]);
            }
        }
    }

    const float sc = scale[0];
    const size_t obase =
        (size_t)b * (COUT * H_ * W_) + (size_t)(oh * W_ + ow);
#pragma unroll
    for (int co = 0; co < COUT; ++co)
        out[obase + (size_t)co * (H_ * W_)] = sc * (acc[co] + bias[co]);
}

extern "C" void kernel_launch(void* const* d_in, const int* in_sizes, int n_in,
                              void* d_out, int out_size, void* d_ws,
                              size_t ws_size, hipStream_t stream) {
    const float* x     = (const float*)d_in[0];
    const float* w     = (const float*)d_in[1];
    const float* bias  = (const float*)d_in[2];
    const float* scale = (const float*)d_in[3];
    float* out         = (float*)d_out;

    const size_t wq_bytes = (size_t)COUT * CIN * 9 * sizeof(float);  // 147456

    if (ws_size >= wq_bytes) {
        float* wq = (float*)d_ws;
        quantize_transpose_w<<<(COUT * CIN * 9 + 255) / 256, 256, 0, stream>>>(
            w, wq);
        conv3x3_direct<true>
            <<<B_ * TPB, 256, 0, stream>>>(x, wq, bias, scale, out);
    } else {
        // Fallback: no workspace — read original layout, sign inline.
        conv3x3_direct<false>
            <<<B_ * TPB, 256, 0, stream>>>(x, w, bias, scale, out);
    }
}

// Round 2
// 111.704 us; speedup vs baseline: 9.2233x; 9.2233x over previous
//
#include <hip/hip_runtime.h>

#define B_ 32
#define C_ 64          // Cin = Cout = 64
#define H_ 112
#define W_ 112
#define HW (H_ * W_)
#define ROWS 2
#define HTILES (H_ / ROWS)   // 56
#define NBLK (B_ * HTILES)   // 1792

// LDS x-tile: [4 rows][114 cols][cin] bf16, spatial stride padded to 144 B
// (72 bf16 slots, 64 used). 144 B = 36 dwords -> bank rotation 4/spatial ->
// ds_read_b128 B-frags perfectly bank-balanced. 16B-aligned stride.
#define XR 4
#define XC 114
#define SPSTR 144                      // bytes per spatial position
#define LDS_BYTES (XR * XC * SPSTR)    // 65664

typedef short bf16x8 __attribute__((ext_vector_type(8)));
typedef float f32x4 __attribute__((ext_vector_type(4)));

__device__ inline unsigned short f2bf(float f) {
    union { float f; unsigned u; } v;
    v.f = f;
    unsigned u = v.u;
    u += 0x7fffu + ((u >> 16) & 1u);   // round-to-nearest-even
    return (unsigned short)(u >> 16);
}

// ---------------------------------------------------------------------------
// Pre-kernel: w[co][cin][kh][kw] fp32 -> wq[shift][co][cin] bf16 (sign).
// cin contiguous => A-fragment = 16B contiguous load per lane.
// ---------------------------------------------------------------------------
__global__ void quant_w(const float* __restrict__ w,
                        unsigned short* __restrict__ wq) {
    int i = blockIdx.x * 256 + threadIdx.x;   // over C_*C_*9
    if (i >= C_ * C_ * 9) return;
    int k   = i % 9;
    int cin = (i / 9) % C_;
    int co  = i / (9 * C_);
    float v = w[i];
    float q = (v > 0.f) ? 1.f : ((v < 0.f) ? -1.f : 0.f);
    wq[(k * C_ + co) * C_ + cin] = f2bf(q);
}

// ---------------------------------------------------------------------------
// Implicit-GEMM conv: M=64 (cout), N=224 (2 rows x 112 cols), K=576.
// Block = 256 threads = 4 waves; wave handles nf == wave (mod 4), all 4 M-frags.
// ---------------------------------------------------------------------------
__global__ __launch_bounds__(256) void conv_mfma(
    const float* __restrict__ x, const unsigned short* __restrict__ wq,
    const float* __restrict__ bias, const float* __restrict__ scale,
    float* __restrict__ out) {
    __shared__ unsigned short xs[LDS_BYTES / 2];

    const int tid  = threadIdx.x;
    const int lane = tid & 63;
    const int wave = tid >> 6;
    const int lcol = lane & 15;
    const int kg   = lane >> 4;

    // XCD-bijective swizzle (NBLK % 8 == 0): consecutive s on same XCD,
    // s-order is h-adjacent -> halo rows hit the same L2.
    const int bid = blockIdx.x;
    const int s   = (bid & 7) * (NBLK / 8) + (bid >> 3);
    const int b   = s / HTILES;
    const int h0  = (s % HTILES) * ROWS;

    // ---- zero LDS (halo cols / out-of-image rows must be 0) ----
    {
        float4* p = (float4*)xs;
        const float4 z = make_float4(0.f, 0.f, 0.f, 0.f);
        for (int i = tid; i < LDS_BYTES / 16; i += 256) p[i] = z;
    }
    __syncthreads();

    // ---- stage x: wave w stages x-row h0-1+w, all 64 cin, transposed ----
    {
        const int xrow = h0 - 1 + wave;
        if (0 <= xrow && xrow < H_) {
            const float* xr = x + (size_t)b * C_ * HW + (size_t)xrow * W_;
            char* xsb = (char*)xs;
            for (int cp = 0; cp < 32; ++cp) {
                const float* p0 = xr + (size_t)(2 * cp) * HW;
                const float* p1 = xr + (size_t)(2 * cp + 1) * HW;
#pragma unroll
                for (int pass = 0; pass < 2; ++pass) {
                    const int col = pass ? (lane + 48) : lane;  // covers 0..111
                    float a0 = p0[col];
                    float a1 = p1[col];
                    unsigned pk =
                        (unsigned)f2bf(a0) | ((unsigned)f2bf(a1) << 16);
                    *(unsigned*)(xsb + (wave * XC + col + 1) * SPSTR + cp * 4) =
                        pk;
                }
            }
        }
    }
    __syncthreads();

    // ---- N-frag assignment: nf = wave + 4*i ----
    int nfoff[4];
#pragma unroll
    for (int i = 0; i < 4; ++i) {
        const int nf  = wave + 4 * i;
        const int nfr = (nf >= 7) ? 1 : 0;
        const int nfc = nf - 7 * nfr;
        nfoff[i] = (nfr * XC + nfc * 16) * SPSTR;
    }

    f32x4 acc[4][4];   // [m][i]
#pragma unroll
    for (int m = 0; m < 4; ++m)
#pragma unroll
        for (int i = 0; i < 4; ++i) {
            f32x4 z = {0.f, 0.f, 0.f, 0.f};
            acc[m][i] = z;
        }

    const char* xsb = (const char*)xs;

    for (int dh = -1; dh <= 1; ++dh) {
        for (int dw = -1; dw <= 1; ++dw) {
            const unsigned short* wbase =
                wq + ((dh + 1) * 3 + (dw + 1)) * C_ * C_ + lcol * C_ + kg * 8;
            const int soff =
                ((1 + dh) * XC + (lcol + 1) + dw) * SPSTR + kg * 16;
#pragma unroll
            for (int c0 = 0; c0 < 2; ++c0) {
                const bf16x8 af0 = *(const bf16x8*)(wbase + c0 * 32);
                const bf16x8 af1 = *(const bf16x8*)(wbase + c0 * 32 + 16 * C_);
                const bf16x8 af2 = *(const bf16x8*)(wbase + c0 * 32 + 32 * C_);
                const bf16x8 af3 = *(const bf16x8*)(wbase + c0 * 32 + 48 * C_);
#pragma unroll
                for (int i = 0; i < 4; ++i) {
                    if (wave + 4 * i < 14) {   // wave-uniform guard
                        const bf16x8 bv = *(const bf16x8*)(xsb + soff +
                                                           nfoff[i] + c0 * 64);
                        acc[0][i] = __builtin_amdgcn_mfma_f32_16x16x32_bf16(
                            af0, bv, acc[0][i], 0, 0, 0);
                        acc[1][i] = __builtin_amdgcn_mfma_f32_16x16x32_bf16(
                            af1, bv, acc[1][i], 0, 0, 0);
                        acc[2][i] = __builtin_amdgcn_mfma_f32_16x16x32_bf16(
                            af2, bv, acc[2][i], 0, 0, 0);
                        acc[3][i] = __builtin_amdgcn_mfma_f32_16x16x32_bf16(
                            af3, bv, acc[3][i], 0, 0, 0);
                    }
                }
            }
        }
    }

    // ---- epilogue: out[b][cout][h][w] = scale * (acc + bias[cout]) ----
    const float sc = scale[0];
    f32x4 bv[4];
#pragma unroll
    for (int m = 0; m < 4; ++m)
        bv[m] = *(const f32x4*)(bias + m * 16 + kg * 4);   // 16B-aligned

#pragma unroll
    for (int i = 0; i < 4; ++i) {
        const int nf = wave + 4 * i;
        if (nf < 14) {
            const int nfr  = (nf >= 7) ? 1 : 0;
            const int nfc  = nf - 7 * nfr;
            const int h    = h0 + nfr;
            const int colb = nfc * 16 + lcol;
#pragma unroll
            for (int m = 0; m < 4; ++m) {
#pragma unroll
                for (int r = 0; r < 4; ++r) {
                    const int cout = m * 16 + kg * 4 + r;
                    out[((size_t)b * C_ + cout) * HW + h * W_ + colb] =
                        sc * (acc[m][i][r] + bv[m][r]);
                }
            }
        }
    }
}

extern "C" void kernel_launch(void* const* d_in, const int* in_sizes, int n_in,
                              void* d_out, int out_size, void* d_ws,
                              size_t ws_size, hipStream_t stream) {
    const float* x     = (const float*)d_in[0];
    const float* w     = (const float*)d_in[1];
    const float* bias  = (const float*)d_in[2];
    const float* scale = (const float*)d_in[3];
    float* out         = (float*)d_out;

    unsigned short* wq = (unsigned short*)d_ws;   // 9*64*64*2 = 73728 B

    quant_w<<<(C_ * C_ * 9 + 255) / 256, 256, 0, stream>>>(w, wq);
    conv_mfma<<<NBLK, 256, 0, stream>>>(x, wq, bias, scale, out);
}